// Round 8
// baseline (501.841 us; speedup 1.0000x reference)
//
#include <hip/hip_runtime.h>
#include <hip/hip_bf16.h>

#define INDIM 256
#define OUTDIM 128
#define BUCKET_CAP 64

typedef __attribute__((ext_vector_type(4))) float f32x4;
typedef __attribute__((ext_vector_type(8))) short bf16x8;

__device__ inline ushort f2bf(float x) {
  __hip_bfloat16 h = __float2bfloat16(x);
  return *reinterpret_cast<ushort*>(&h);
}

// Convert + transpose weights to bf16 (w1t[col][k], w2t[col][k]) so MFMA
// B-fragments (8 contiguous k per lane) are 16B vector loads.
__global__ void convert_weights_k(const float* __restrict__ W1, const float* __restrict__ W2,
                                  ushort* __restrict__ w1t, ushort* __restrict__ w2t) {
  int i = blockIdx.x * blockDim.x + threadIdx.x;
  if (i < INDIM * OUTDIM) {
    int col = i / INDIM, k = i % INDIM;
    w1t[i] = f2bf(W1[k * OUTDIM + col]);
  }
  if (i < OUTDIM * OUTDIM) {
    int col = i / OUTDIM, k = i % OUTDIM;
    w2t[i] = f2bf(W2[k * OUTDIM + col]);
  }
}

// t = tanh(F @ W1 + b1)  — 64-row tile per block, 4 waves x 16 rows, full N=128.
__global__ __launch_bounds__(256) void mlp1_k(const float* __restrict__ feat,
      const ushort* __restrict__ w1t, const float* __restrict__ b1,
      ushort* __restrict__ t_ws, int n) {
  __shared__ ushort As[64 * 256];  // bf16, XOR-swizzled (row&7)<<4 on byte offset
  const int tid = threadIdx.x;
  const int row0 = blockIdx.x * 64;
  #pragma unroll
  for (int s = 0; s < 16; ++s) {
    int e = s * 1024 + tid * 4;       // flat elem index; coalesced 16B/lane
    int r = e >> 8, c = e & 255;
    int gr = row0 + r;
    float4 f = make_float4(0.f, 0.f, 0.f, 0.f);
    if (gr < n) f = *reinterpret_cast<const float4*>(feat + (size_t)gr * INDIM + c);
    ushort4 u;
    u.x = f2bf(f.x); u.y = f2bf(f.y); u.z = f2bf(f.z); u.w = f2bf(f.w);
    int bo = (r * 512 + c * 2) ^ ((r & 7) << 4);
    *reinterpret_cast<ushort4*>(reinterpret_cast<char*>(As) + bo) = u;
  }
  __syncthreads();
  const int wave = tid >> 6, lane = tid & 63;
  const int l15 = lane & 15, lhi = lane >> 4;
  const int arow = wave * 16 + l15;
  f32x4 acc[8];
  #pragma unroll
  for (int nt = 0; nt < 8; ++nt) acc[nt] = (f32x4){0.f, 0.f, 0.f, 0.f};
  #pragma unroll
  for (int ks = 0; ks < 8; ++ks) {
    int kk = ks * 32 + lhi * 8;
    int ao = (arow * 512 + kk * 2) ^ ((arow & 7) << 4);
    bf16x8 afrag = *reinterpret_cast<bf16x8*>(reinterpret_cast<char*>(As) + ao);
    #pragma unroll
    for (int nt = 0; nt < 8; ++nt) {
      int bcol = nt * 16 + l15;
      bf16x8 bfrag = *reinterpret_cast<const bf16x8*>(w1t + bcol * INDIM + kk);
      acc[nt] = __builtin_amdgcn_mfma_f32_16x16x32_bf16(afrag, bfrag, acc[nt], 0, 0, 0);
    }
  }
  #pragma unroll
  for (int nt = 0; nt < 8; ++nt) {
    #pragma unroll
    for (int r = 0; r < 4; ++r) {
      int gr = row0 + wave * 16 + lhi * 4 + r;   // D: row=(lane>>4)*4+reg, col=lane&15
      if (gr < n) {
        int col = nt * 16 + l15;
        float v = acc[nt][r] + b1[col];
        t_ws[(size_t)gr * OUTDIM + col] = f2bf(tanhf(v));
      }
    }
  }
}

// h = t @ W2 + b2
__global__ __launch_bounds__(256) void mlp2_k(const ushort* __restrict__ t_ws,
      const ushort* __restrict__ w2t, const float* __restrict__ b2,
      ushort* __restrict__ h_ws, int n) {
  __shared__ ushort As[64 * 128];
  const int tid = threadIdx.x;
  const int row0 = blockIdx.x * 64;
  #pragma unroll
  for (int s = 0; s < 4; ++s) {
    int e = s * 2048 + tid * 8;
    int r = e >> 7, c = e & 127;
    int gr = row0 + r;
    bf16x8 v = (bf16x8){0, 0, 0, 0, 0, 0, 0, 0};
    if (gr < n) v = *reinterpret_cast<const bf16x8*>(t_ws + (size_t)gr * OUTDIM + c);
    int bo = (r * 256 + c * 2) ^ ((r & 7) << 4);
    *reinterpret_cast<bf16x8*>(reinterpret_cast<char*>(As) + bo) = v;
  }
  __syncthreads();
  const int wave = tid >> 6, lane = tid & 63;
  const int l15 = lane & 15, lhi = lane >> 4;
  const int arow = wave * 16 + l15;
  f32x4 acc[8];
  #pragma unroll
  for (int nt = 0; nt < 8; ++nt) acc[nt] = (f32x4){0.f, 0.f, 0.f, 0.f};
  #pragma unroll
  for (int ks = 0; ks < 4; ++ks) {
    int kk = ks * 32 + lhi * 8;
    int ao = (arow * 256 + kk * 2) ^ ((arow & 7) << 4);
    bf16x8 afrag = *reinterpret_cast<bf16x8*>(reinterpret_cast<char*>(As) + ao);
    #pragma unroll
    for (int nt = 0; nt < 8; ++nt) {
      int bcol = nt * 16 + l15;
      bf16x8 bfrag = *reinterpret_cast<const bf16x8*>(w2t + bcol * OUTDIM + kk);
      acc[nt] = __builtin_amdgcn_mfma_f32_16x16x32_bf16(afrag, bfrag, acc[nt], 0, 0, 0);
    }
  }
  #pragma unroll
  for (int nt = 0; nt < 8; ++nt) {
    #pragma unroll
    for (int r = 0; r < 4; ++r) {
      int gr = row0 + wave * 16 + lhi * 4 + r;
      if (gr < n) {
        int col = nt * 16 + l15;
        float v = acc[nt][r] + b2[col];
        h_ws[(size_t)gr * OUTDIM + col] = f2bf(v);
      }
    }
  }
}

// CSR-free bucketing: one int atomic per edge. Poisson(16) degree => cap 64 safe
// (P(deg>=64) ~ e^-40 per node).
__global__ void scatter_k(const int* __restrict__ edges, int E, int* __restrict__ cnt,
                          int* __restrict__ bucket) {
  int i = blockIdx.x * blockDim.x + threadIdx.x;
  if (i < E) {
    int2 e = reinterpret_cast<const int2*>(edges)[i];
    int p = atomicAdd(&cnt[e.x], 1);
    if (p < BUCKET_CAP) bucket[e.x * BUCKET_CAP + p] = e.y;
  }
}

// One wave per output row; 2 cols/lane; dst list held in lane regs + __shfl broadcast.
__global__ __launch_bounds__(256) void aggregate_k(const ushort* __restrict__ h,
      const int* __restrict__ nodes, const int* __restrict__ cnt,
      const int* __restrict__ bucket, const int* __restrict__ indp,
      float* __restrict__ out, int nout) {
  int gtid = blockIdx.x * blockDim.x + threadIdx.x;
  int wid = gtid >> 6;
  int lane = gtid & 63;
  if (wid >= nout) return;
  int s = nodes[wid];
  int ind = indp[0] & 3;
  float mv = (ind < 2) ? 1.0f : 0.0f;  // MASK = (1,1,0,0)
  int deg = min(cnt[s], BUCKET_CAP);
  int myd = (lane < deg) ? bucket[s * BUCKET_CAP + lane] : -1;
  float a0 = 0.f, a1 = 0.f, wsum = 0.f;
  for (int e = 0; e < deg; ++e) {
    int d = __shfl(myd, e);
    float w = (d == s) ? mv : 1.0f;
    wsum += w;
    if (w != 0.f) {
      uint u = *reinterpret_cast<const uint*>(h + (size_t)d * OUTDIM + lane * 2);
      a0 += w * __uint_as_float(u << 16);
      a1 += w * __uint_as_float(u & 0xffff0000u);
    }
  }
  float rs = (wsum == 0.f) ? 1.f : wsum;
  float2 o;
  o.x = a0 / rs;
  o.y = a1 / rs;
  *reinterpret_cast<float2*>(out + (size_t)wid * OUTDIM + lane * 2) = o;
}

extern "C" void kernel_launch(void* const* d_in, const int* in_sizes, int n_in,
                              void* d_out, int out_size, void* d_ws, size_t ws_size,
                              hipStream_t stream) {
  const float* feat  = (const float*)d_in[0];
  const float* W1    = (const float*)d_in[1];
  const float* b1    = (const float*)d_in[2];
  const float* W2    = (const float*)d_in[3];
  const float* b2    = (const float*)d_in[4];
  const int*   nodes = (const int*)d_in[5];
  const int*   edges = (const int*)d_in[6];
  const int*   indp  = (const int*)d_in[7];
  const int nnodes = in_sizes[0] / INDIM;
  const int E = in_sizes[6] / 2;
  const int nout = out_size / OUTDIM;

  char* ws = (char*)d_ws;
  size_t off = 0;
  auto alloc = [&](size_t b) { size_t r = off; off += (b + 255) & ~(size_t)255; return r; };
  ushort* w1t   = (ushort*)(ws + alloc((size_t)INDIM * OUTDIM * 2));
  ushort* w2t   = (ushort*)(ws + alloc((size_t)OUTDIM * OUTDIM * 2));
  ushort* h_ws  = (ushort*)(ws + alloc((size_t)nnodes * OUTDIM * 2));
  int*    cnt   = (int*)(ws + alloc((size_t)nnodes * 4));
  // t_ws is dead after mlp2_k and scatter_k runs after mlp2_k -> alias
  // bucket onto t_ws (both 25.6 MB) to halve workspace demand.
  size_t shared_off = alloc((size_t)nnodes * BUCKET_CAP * 4);   // >= nnodes*OUTDIM*2
  ushort* t_ws   = (ushort*)(ws + shared_off);
  int*    bucket = (int*)(ws + shared_off);

  hipMemsetAsync(cnt, 0, (size_t)nnodes * 4, stream);
  convert_weights_k<<<(INDIM * OUTDIM + 255) / 256, 256, 0, stream>>>(W1, W2, w1t, w2t);
  mlp1_k<<<(nnodes + 63) / 64, 256, 0, stream>>>(feat, w1t, b1, t_ws, nnodes);
  mlp2_k<<<(nnodes + 63) / 64, 256, 0, stream>>>(t_ws, w2t, b2, h_ws, nnodes);
  scatter_k<<<(E + 255) / 256, 256, 0, stream>>>(edges, E, cnt, bucket);
  aggregate_k<<<(nout + 3) / 4, 256, 0, stream>>>(h_ws, nodes, cnt, bucket, indp,
                                                  (float*)d_out, nout);
}

// Round 14
// 424.121 us; speedup vs baseline: 1.1833x; 1.1833x over previous
//
#include <hip/hip_runtime.h>
#include <hip/hip_bf16.h>

#define INDIM 256
#define OUTDIM 128
#define BUCKET_CAP 64

typedef __attribute__((ext_vector_type(4))) float f32x4;
typedef __attribute__((ext_vector_type(8))) short bf16x8;

__device__ inline ushort f2bf(float x) {
  __hip_bfloat16 h = __float2bfloat16(x);
  return *reinterpret_cast<ushort*>(&h);
}

// Convert+transpose weights to bf16 AND zero cnt (folds old memset dispatch).
__global__ void prep_k(const float* __restrict__ W1, const float* __restrict__ W2,
                       ushort* __restrict__ w1t, ushort* __restrict__ w2t,
                       int* __restrict__ cnt, int n) {
  int i = blockIdx.x * blockDim.x + threadIdx.x;
  if (i < INDIM * OUTDIM) {
    int col = i / INDIM, k = i % INDIM;
    w1t[i] = f2bf(W1[k * OUTDIM + col]);
  }
  if (i < OUTDIM * OUTDIM) {
    int col = i / OUTDIM, k = i % OUTDIM;
    w2t[i] = f2bf(W2[k * OUTDIM + col]);
  }
  if (i < n) cnt[i] = 0;
}

// Grid-fused: blocks [0,nscat) do edge-bucket scatter; blocks [nscat,..) each
// compute BOTH MLP layers for a 64-row tile (t lives only in LDS).
// Scatter (HBM-scatter-bound) overlaps MLP (MFMA-bound) in one dispatch.
__global__ __launch_bounds__(256) void fused_k(
      const float* __restrict__ feat, const ushort* __restrict__ w1t,
      const float* __restrict__ b1, const ushort* __restrict__ w2t,
      const float* __restrict__ b2, ushort* __restrict__ h_ws, int n,
      const int* __restrict__ edges, int E, int* __restrict__ cnt,
      int* __restrict__ bucket, int nscat) {
  const int tid = threadIdx.x;
  const int bid = blockIdx.x;
  if (bid < nscat) {
    // CSR-free bucketing: one int atomic per edge; cap 64 vs Poisson(16) degree.
    const int stride = nscat << 8;
    for (int i = (bid << 8) + tid; i < E; i += stride) {
      int2 e = reinterpret_cast<const int2*>(edges)[i];
      int p = atomicAdd(&cnt[e.x], 1);
      if (p < BUCKET_CAP) bucket[e.x * BUCKET_CAP + p] = e.y;
    }
    return;
  }
  __shared__ ushort As[64 * 256];  // stage A (bf16, XOR-swizzled); reused for t
  const int row0 = (bid - nscat) * 64;
  #pragma unroll
  for (int s = 0; s < 16; ++s) {
    int e = s * 1024 + tid * 4;
    int r = e >> 8, c = e & 255;
    int gr = row0 + r;
    float4 f = make_float4(0.f, 0.f, 0.f, 0.f);
    if (gr < n) f = *reinterpret_cast<const float4*>(feat + (size_t)gr * INDIM + c);
    ushort4 u;
    u.x = f2bf(f.x); u.y = f2bf(f.y); u.z = f2bf(f.z); u.w = f2bf(f.w);
    int bo = (r * 512 + c * 2) ^ ((r & 7) << 4);
    *reinterpret_cast<ushort4*>(reinterpret_cast<char*>(As) + bo) = u;
  }
  __syncthreads();
  const int wave = tid >> 6, lane = tid & 63;
  const int l15 = lane & 15, lhi = lane >> 4;
  const int arow = wave * 16 + l15;
  // ---- layer 1: t = tanh(F@W1 + b1) ----
  f32x4 acc[8];
  #pragma unroll
  for (int nt = 0; nt < 8; ++nt) acc[nt] = (f32x4){0.f, 0.f, 0.f, 0.f};
  #pragma unroll
  for (int ks = 0; ks < 8; ++ks) {
    int kk = ks * 32 + lhi * 8;
    int ao = (arow * 512 + kk * 2) ^ ((arow & 7) << 4);
    bf16x8 afrag = *reinterpret_cast<bf16x8*>(reinterpret_cast<char*>(As) + ao);
    #pragma unroll
    for (int nt = 0; nt < 8; ++nt) {
      int bcol = nt * 16 + l15;
      bf16x8 bfrag = *reinterpret_cast<const bf16x8*>(w1t + bcol * INDIM + kk);
      acc[nt] = __builtin_amdgcn_mfma_f32_16x16x32_bf16(afrag, bfrag, acc[nt], 0, 0, 0);
    }
  }
  __syncthreads();   // all layer-1 LDS reads complete before overwriting As
  // t tile -> LDS [64][128] bf16, same swizzle family as the old mlp2 A-tile.
  #pragma unroll
  for (int nt = 0; nt < 8; ++nt) {
    #pragma unroll
    for (int r = 0; r < 4; ++r) {
      int row = wave * 16 + lhi * 4 + r;   // D: row=(lane>>4)*4+reg, col=lane&15
      int col = nt * 16 + l15;
      float v = acc[nt][r] + b1[col];
      ushort tv = f2bf(tanhf(v));
      int bo = (row * 256 + col * 2) ^ ((row & 7) << 4);
      *reinterpret_cast<ushort*>(reinterpret_cast<char*>(As) + bo) = tv;
    }
  }
  __syncthreads();
  // ---- layer 2: h = t@W2 + b2 ----
  f32x4 acc2[8];
  #pragma unroll
  for (int nt = 0; nt < 8; ++nt) acc2[nt] = (f32x4){0.f, 0.f, 0.f, 0.f};
  #pragma unroll
  for (int ks = 0; ks < 4; ++ks) {
    int kk = ks * 32 + lhi * 8;
    int ao = (arow * 256 + kk * 2) ^ ((arow & 7) << 4);
    bf16x8 afrag = *reinterpret_cast<bf16x8*>(reinterpret_cast<char*>(As) + ao);
    #pragma unroll
    for (int nt = 0; nt < 8; ++nt) {
      int bcol = nt * 16 + l15;
      bf16x8 bfrag = *reinterpret_cast<const bf16x8*>(w2t + bcol * OUTDIM + kk);
      acc2[nt] = __builtin_amdgcn_mfma_f32_16x16x32_bf16(afrag, bfrag, acc2[nt], 0, 0, 0);
    }
  }
  #pragma unroll
  for (int nt = 0; nt < 8; ++nt) {
    #pragma unroll
    for (int r = 0; r < 4; ++r) {
      int gr = row0 + wave * 16 + lhi * 4 + r;
      if (gr < n) {
        int col = nt * 16 + l15;
        float v = acc2[nt][r] + b2[col];
        h_ws[(size_t)gr * OUTDIM + col] = f2bf(v);
      }
    }
  }
}

// One wave per output row; 2 cols/lane; dst list in lane regs + __shfl broadcast.
// 2-edge unroll: two independent h-row gathers in flight per iteration.
__global__ __launch_bounds__(256) void aggregate_k(const ushort* __restrict__ h,
      const int* __restrict__ nodes, const int* __restrict__ cnt,
      const int* __restrict__ bucket, const int* __restrict__ indp,
      float* __restrict__ out, int nout) {
  int gtid = blockIdx.x * blockDim.x + threadIdx.x;
  int wid = gtid >> 6;
  int lane = gtid & 63;
  if (wid >= nout) return;
  int s = nodes[wid];
  int ind = indp[0] & 3;
  float mv = (ind < 2) ? 1.0f : 0.0f;  // MASK = (1,1,0,0)
  int deg = min(cnt[s], BUCKET_CAP);
  int myd = (lane < deg) ? bucket[s * BUCKET_CAP + lane] : -1;
  float a0 = 0.f, a1 = 0.f, wsum = 0.f;
  int e = 0;
  for (; e + 2 <= deg; e += 2) {
    int d0 = __shfl(myd, e);
    int d1 = __shfl(myd, e + 1);
    float w0 = (d0 == s) ? mv : 1.0f;
    float w1v = (d1 == s) ? mv : 1.0f;
    uint u0 = *reinterpret_cast<const uint*>(h + (size_t)d0 * OUTDIM + lane * 2);
    uint u1 = *reinterpret_cast<const uint*>(h + (size_t)d1 * OUTDIM + lane * 2);
    wsum += w0 + w1v;
    a0 += w0 * __uint_as_float(u0 << 16) + w1v * __uint_as_float(u1 << 16);
    a1 += w0 * __uint_as_float(u0 & 0xffff0000u) + w1v * __uint_as_float(u1 & 0xffff0000u);
  }
  if (e < deg) {
    int d = __shfl(myd, e);
    float w = (d == s) ? mv : 1.0f;
    uint u = *reinterpret_cast<const uint*>(h + (size_t)d * OUTDIM + lane * 2);
    wsum += w;
    a0 += w * __uint_as_float(u << 16);
    a1 += w * __uint_as_float(u & 0xffff0000u);
  }
  float rs = (wsum == 0.f) ? 1.f : wsum;
  float2 o;
  o.x = a0 / rs;
  o.y = a1 / rs;
  *reinterpret_cast<float2*>(out + (size_t)wid * OUTDIM + lane * 2) = o;
}

extern "C" void kernel_launch(void* const* d_in, const int* in_sizes, int n_in,
                              void* d_out, int out_size, void* d_ws, size_t ws_size,
                              hipStream_t stream) {
  const float* feat  = (const float*)d_in[0];
  const float* W1    = (const float*)d_in[1];
  const float* b1    = (const float*)d_in[2];
  const float* W2    = (const float*)d_in[3];
  const float* b2    = (const float*)d_in[4];
  const int*   nodes = (const int*)d_in[5];
  const int*   edges = (const int*)d_in[6];
  const int*   indp  = (const int*)d_in[7];
  const int nnodes = in_sizes[0] / INDIM;
  const int E = in_sizes[6] / 2;
  const int nout = out_size / OUTDIM;

  char* ws = (char*)d_ws;
  size_t off = 0;
  auto alloc = [&](size_t b) { size_t r = off; off += (b + 255) & ~(size_t)255; return r; };
  ushort* w1t    = (ushort*)(ws + alloc((size_t)INDIM * OUTDIM * 2));
  ushort* w2t    = (ushort*)(ws + alloc((size_t)OUTDIM * OUTDIM * 2));
  ushort* h_ws   = (ushort*)(ws + alloc((size_t)nnodes * OUTDIM * 2));
  int*    cnt    = (int*)(ws + alloc((size_t)nnodes * 4));
  int*    bucket = (int*)(ws + alloc((size_t)nnodes * BUCKET_CAP * 4));

  const int nscat = 1664;                      // 8-aligned; ~4 edges/thread
  const int nmlp  = (nnodes + 63) / 64;
  prep_k<<<(nnodes + 255) / 256, 256, 0, stream>>>(W1, W2, w1t, w2t, cnt, nnodes);
  fused_k<<<nscat + nmlp, 256, 0, stream>>>(feat, w1t, b1, w2t, b2, h_ws, nnodes,
                                            edges, E, cnt, bucket, nscat);
  aggregate_k<<<(nout + 3) / 4, 256, 0, stream>>>(h_ws, nodes, cnt, bucket, indp,
                                                  (float*)d_out, nout);
}